// Round 7
// baseline (266.560 us; speedup 1.0000x reference)
//
#include <hip/hip_runtime.h>

#define T_   2048
#define BB   2
#define CC   2048
#define HH   16
#define GG   4
#define HSS  128
#define QKVD 3072          // (H+2G)*HS
#define NQKV 3088          // + H gate cols
#define NPAD 3200          // padded to 25*128
#define SCALE_ 0.08838834764831845f   // 1/sqrt(128)
#define SCALE2_ (0.08838834764831845f * 1.4426950408889634f)   // 1/sqrt(128) * log2(e)

typedef __attribute__((ext_vector_type(8))) short  short8;
typedef __attribute__((ext_vector_type(4))) float  f32x4;
typedef __attribute__((ext_vector_type(4))) int    v4i;
typedef __attribute__((ext_vector_type(4))) float  v4f;
typedef __attribute__((ext_vector_type(4))) unsigned short u16x4;

typedef const void __attribute__((address_space(1)))* gas1_t;
typedef void __attribute__((address_space(3)))* as3_t;

__device__ __forceinline__ void gl_lds16(const void* g, void* l) {
    __builtin_amdgcn_global_load_lds((gas1_t)g, (as3_t)l, 16, 0, 0);
}

__device__ __forceinline__ unsigned short f2bf(float f) {
    unsigned u = __float_as_uint(f);
    u += 0x7fffu + ((u >> 16) & 1u);   // RNE
    return (unsigned short)(u >> 16);
}
__device__ __forceinline__ float bf2f(unsigned short h) {
    return __uint_as_float(((unsigned)h) << 16);
}

// ---------------- f32 -> bf16 convert (with optional zero-pad tail) ----------------
__global__ void k_convert(const float* __restrict__ src, unsigned short* __restrict__ dst,
                          int n_src4, int n_dst4) {
    int i = blockIdx.x * blockDim.x + threadIdx.x;
    if (i >= n_dst4) return;
    u16x4 o;
    if (i < n_src4) {
        v4f v = *(const v4f*)(src + (size_t)i * 4);
        o[0] = f2bf(v[0]); o[1] = f2bf(v[1]); o[2] = f2bf(v[2]); o[3] = f2bf(v[3]);
    } else {
        o[0] = 0; o[1] = 0; o[2] = 0; o[3] = 0;
    }
    *(u16x4*)(dst + (size_t)i * 4) = o;
}

// ---------------- NT GEMM: C[m][n] = sum_k A[m][k]*B[n][k], bf16 in ----------------
template <typename OutT>
__launch_bounds__(256, 2)
__global__ void k_gemm_nt(const unsigned short* __restrict__ A,
                          const unsigned short* __restrict__ Bm,
                          OutT* __restrict__ C,
                          int K, int lda, int ldb, int ldc) {
    __shared__ unsigned short As[128 * 64];
    __shared__ unsigned short Bs[128 * 64];
    const int t    = threadIdx.x;
    const int lane = t & 63;
    const int wid  = t >> 6;
    const int bm = blockIdx.x, bn = blockIdx.y;
    const int wm = (wid >> 1) * 64, wn = (wid & 1) * 64;

    f32x4 acc[4][4];
#pragma unroll
    for (int i = 0; i < 4; ++i)
#pragma unroll
        for (int j = 0; j < 4; ++j)
            acc[i][j] = (f32x4){0.f, 0.f, 0.f, 0.f};

    const int fro = lane & 15;
    const int fko = (lane >> 4) * 8;
    const int lrow = lane >> 3, lcol = (lane & 7) * 8;

    for (int kt = 0; kt < K; kt += 64) {
        __syncthreads();
#pragma unroll
        for (int p = 0; p < 4; ++p) {
            const int ra = wid * 32 + p * 8;
            gl_lds16(A  + (size_t)(bm * 128 + ra + lrow) * lda + kt + lcol, &As[ra * 64]);
            gl_lds16(Bm + (size_t)(bn * 128 + ra + lrow) * ldb + kt + lcol, &Bs[ra * 64]);
        }
        __syncthreads();
#pragma unroll
        for (int kk = 0; kk < 2; ++kk) {
            short8 af[4], bfr[4];
#pragma unroll
            for (int i = 0; i < 4; ++i)
                af[i] = *(const short8*)&As[(wm + i * 16 + fro) * 64 + kk * 32 + fko];
#pragma unroll
            for (int j = 0; j < 4; ++j)
                bfr[j] = *(const short8*)&Bs[(wn + j * 16 + fro) * 64 + kk * 32 + fko];
#pragma unroll
            for (int i = 0; i < 4; ++i)
#pragma unroll
                for (int j = 0; j < 4; ++j)
                    acc[i][j] = __builtin_amdgcn_mfma_f32_16x16x32_bf16(af[i], bfr[j], acc[i][j], 0, 0, 0);
        }
    }
    const int col = lane & 15, rbase = (lane >> 4) * 4;
#pragma unroll
    for (int i = 0; i < 4; ++i)
#pragma unroll
        for (int j = 0; j < 4; ++j)
#pragma unroll
            for (int r = 0; r < 4; ++r) {
                int grow = bm * 128 + wm + i * 16 + rbase + r;
                int gcol = bn * 128 + wn + j * 16 + col;
                float v = acc[i][j][r];
                if constexpr (sizeof(OutT) == 2)
                    C[(size_t)grow * ldc + gcol] = (OutT)f2bf(v);
                else
                    C[(size_t)grow * ldc + gcol] = (OutT)v;
            }
}

// ---------------- fused RMSNorm + RoPE, in place on q/k regions of qkv -------------
__global__ void k_normrope(unsigned short* __restrict__ qkv,
                           const float* __restrict__ cosT, const float* __restrict__ sinT,
                           const float* __restrict__ qw, const float* __restrict__ kw) {
    const int lane = threadIdx.x & 63;
    const int row  = blockIdx.x * 4 + (threadIdx.x >> 6);  // 0 .. 4096*20-1
    const int tok  = row / 20;
    const int hh   = row - tok * 20;
    const int tpos = tok & (T_ - 1);
    unsigned short* rp = qkv + (size_t)tok * NPAD + (hh < 16 ? hh * 128 : 2048 + (hh - 16) * 128);
    const float* w = (hh < 16) ? qw : kw;
    float e1 = bf2f(rp[lane]);
    float e2 = bf2f(rp[lane + 64]);
    float ss = e1 * e1 + e2 * e2;
#pragma unroll
    for (int m = 1; m < 64; m <<= 1) ss += __shfl_xor(ss, m);
    float inv = rsqrtf(ss * (1.0f / 128.0f) + 1e-5f);
    float n1 = e1 * inv * w[lane];
    float n2 = e2 * inv * w[lane + 64];
    float c = cosT[tpos * 64 + lane];
    float s = sinT[tpos * 64 + lane];
    rp[lane]      = f2bf(n1 * c - n2 * s);
    rp[lane + 64] = f2bf(n2 * c + n1 * s);
}

// ---------------- V transpose: VT[b][g][d][s] = V[b][s][g][d] ----------------------
__global__ void k_transposeV(const unsigned short* __restrict__ qkv,
                             unsigned short* __restrict__ vt) {
    __shared__ unsigned short tile[64][65];
    const int b = blockIdx.x >> 2, g = blockIdx.x & 3;
    const int s0 = blockIdx.y * 64, d0 = blockIdx.z * 64;
    const int tx = threadIdx.x & 63, ty0 = threadIdx.x >> 6;
    const unsigned short* src = qkv + (size_t)(b * T_ + s0) * NPAD + 2560 + g * 128 + d0;
#pragma unroll
    for (int r = 0; r < 16; ++r) {
        int ty = ty0 * 16 + r;
        tile[ty][tx] = src[(size_t)ty * NPAD + tx];
    }
    __syncthreads();
    unsigned short* dstp = vt + ((size_t)(b * GG + g) * 128 + d0) * T_ + s0;
#pragma unroll
    for (int r = 0; r < 16; ++r) {
        int ty = ty0 * 16 + r;
        dstp[(size_t)ty * T_ + tx] = tile[tx][ty];
    }
}

// ---------------- flash attention + gate ------------------------------------------
// 512 uniform blocks (pair p & 31-p). K/V double-buffered via global_load_lds;
// counted vmcnt(8) + raw barriers (no full drain in the main loop, T4);
// defer-rescale (T13, THR=8 log2); exp2 domain; setprio around MFMA (T5).
__launch_bounds__(256, 2)
__global__ void k_attn(const unsigned short* __restrict__ qkv,
                       const unsigned short* __restrict__ vt,
                       unsigned short* __restrict__ ao) {
    __shared__ unsigned short Ks[2][64 * 128];   // [buf][row kv][slot]  16KB each
    __shared__ unsigned short Vs[2][128 * 64];   // [buf][row d ][slot]  16KB each
    __shared__ unsigned short Ps[4][16 * 76];
    const int t = threadIdx.x;
    const int lane = t & 63;
    const int wid  = t >> 6;
    const int id = blockIdx.x;
    const int bg = id & 7;               // -> XCD (round-robin dispatch assumed)
    const int hh = (id >> 3) & 3;
    const int pr = id >> 5;              // 0..15
    const int b = bg >> 2, g = bg & 3, h = g * 4 + hh;
    const int fro = lane & 15, fk = lane >> 4;
    const int rbase = fk * 4;

    const unsigned short* kg0 = qkv + (size_t)(b * T_) * NPAD + 2048 + g * 128;
    const unsigned short* vg0 = vt + (size_t)(b * GG + g) * 128 * T_;

    const int cp0 = wid * 4;
    int cur = 0;

#pragma unroll
    for (int seg = 0; seg < 2; ++seg) {
        const int qt = (seg == 0) ? pr : 31 - pr;
        const int q0w = qt * 64 + wid * 16;

        // Q fragments: rows q0w+fro, k-chunks kb*32 + fk*8
        short8 qf[4];
        const unsigned short* qp = qkv + (size_t)(b * T_ + q0w + fro) * NPAD + h * 128 + fk * 8;
#pragma unroll
        for (int kb = 0; kb < 4; ++kb) qf[kb] = *(const short8*)(qp + kb * 32);

        float m_r[4], l_r[4];
        f32x4 o[8];
#pragma unroll
        for (int r = 0; r < 4; ++r) { m_r[r] = -1e30f; l_r[r] = 0.f; }
#pragma unroll
        for (int d = 0; d < 8; ++d) o[d] = (f32x4){0.f, 0.f, 0.f, 0.f};

        const int nt = qt + 1;

        // prologue: issue tile 0 into buf[cur] (waited by first loop-iter vmcnt)
#pragma unroll
        for (int p = 0; p < 4; ++p) {
            const int cp = cp0 + p;
            const int kr = cp * 4 + (lane >> 4);
            const int sK = lane & 15;
            gl_lds16(kg0 + (size_t)kr * NPAD + (size_t)((sK ^ (kr & 7)) * 8), &Ks[cur][cp * 512]);
            const int d  = cp * 8 + (lane >> 3);
            const int sV = lane & 7;
            gl_lds16(vg0 + (size_t)d * T_ + (size_t)((sV ^ (d & 7)) * 8), &Vs[cur][cp * 512]);
        }

        for (int ti = 0; ti < nt; ++ti) {
            // issue next tile into buf[cur^1]; counted wait for THIS tile's 8 loads
            if (ti + 1 < nt) {
                const int sn = (ti + 1) * 64;
#pragma unroll
                for (int p = 0; p < 4; ++p) {
                    const int cp = cp0 + p;
                    const int kr = cp * 4 + (lane >> 4);
                    const int sK = lane & 15;
                    gl_lds16(kg0 + (size_t)(sn + kr) * NPAD + (size_t)((sK ^ (kr & 7)) * 8), &Ks[cur ^ 1][cp * 512]);
                    const int d  = cp * 8 + (lane >> 3);
                    const int sV = lane & 7;
                    gl_lds16(vg0 + (size_t)d * T_ + sn + (size_t)((sV ^ (d & 7)) * 8), &Vs[cur ^ 1][cp * 512]);
                }
                asm volatile("s_waitcnt vmcnt(8)" ::: "memory");
            } else {
                asm volatile("s_waitcnt vmcnt(0)" ::: "memory");
            }
            __builtin_amdgcn_s_barrier();
            __builtin_amdgcn_sched_barrier(0);

            // ---- QK^T on buf[cur]: S[16 q][64 kv] ----
            f32x4 sc[4];
#pragma unroll
            for (int jb = 0; jb < 4; ++jb) sc[jb] = (f32x4){0.f, 0.f, 0.f, 0.f};
            __builtin_amdgcn_s_setprio(1);
#pragma unroll
            for (int jb = 0; jb < 4; ++jb) {
                const int kr = jb * 16 + fro;
#pragma unroll
                for (int kb = 0; kb < 4; ++kb) {
                    short8 kf = *(const short8*)&Ks[cur][kr * 128 + 8 * ((kb * 4 + fk) ^ (kr & 7))];
                    sc[jb] = __builtin_amdgcn_mfma_f32_16x16x32_bf16(qf[kb], kf, sc[jb], 0, 0, 0);
                }
            }
            __builtin_amdgcn_s_setprio(0);
            // ---- scale (log2 domain) + causal mask (diagonal tile only) ----
            const bool domask = (ti == qt);
#pragma unroll
            for (int jb = 0; jb < 4; ++jb)
#pragma unroll
                for (int r = 0; r < 4; ++r) {
                    float v = sc[jb][r] * SCALE2_;
                    if (domask && (jb * 16 + fro) > (wid * 16 + rbase + r)) v = -1e30f;
                    sc[jb][r] = v;
                }
            // ---- online softmax with defer-rescale (T13) ----
            float mx[4], rs[4];
#pragma unroll
            for (int r = 0; r < 4; ++r)
                mx[r] = fmaxf(fmaxf(sc[0][r], sc[1][r]), fmaxf(sc[2][r], sc[3][r]));
#pragma unroll
            for (int msk = 1; msk < 16; msk <<= 1)
#pragma unroll
                for (int r = 0; r < 4; ++r) mx[r] = fmaxf(mx[r], __shfl_xor(mx[r], msk));
            bool grow = false;
#pragma unroll
            for (int r = 0; r < 4; ++r) grow = grow || (mx[r] > m_r[r] + 8.f);
            if (__any(grow ? 1 : 0)) {
#pragma unroll
                for (int r = 0; r < 4; ++r) {
                    float mn = fmaxf(m_r[r], mx[r]);
                    float fs = exp2f(m_r[r] - mn);
                    m_r[r] = mn;
                    l_r[r] *= fs;
#pragma unroll
                    for (int d = 0; d < 8; ++d) o[d][r] *= fs;
                }
            }
#pragma unroll
            for (int jb = 0; jb < 4; ++jb)
#pragma unroll
                for (int r = 0; r < 4; ++r) sc[jb][r] = exp2f(sc[jb][r] - m_r[r]);
#pragma unroll
            for (int r = 0; r < 4; ++r)
                rs[r] = (sc[0][r] + sc[1][r]) + (sc[2][r] + sc[3][r]);
#pragma unroll
            for (int msk = 1; msk < 16; msk <<= 1)
#pragma unroll
                for (int r = 0; r < 4; ++r) rs[r] += __shfl_xor(rs[r], msk);
#pragma unroll
            for (int r = 0; r < 4; ++r) l_r[r] += rs[r];
            // ---- P -> LDS (per-wave transpose to A-layout) ----
            unsigned short* pw = &Ps[wid][0];
#pragma unroll
            for (int jb = 0; jb < 4; ++jb)
#pragma unroll
                for (int r = 0; r < 4; ++r)
                    pw[(rbase + r) * 76 + jb * 16 + fro] = f2bf(sc[jb][r]);
            asm volatile("s_waitcnt lgkmcnt(0)" ::: "memory");
            __builtin_amdgcn_sched_barrier(0);
            short8 pa[2];
#pragma unroll
            for (int ks = 0; ks < 2; ++ks)
                pa[ks] = *(const short8*)&Ps[wid][fro * 76 + ks * 32 + fk * 8];
            // ---- PV on buf[cur] ----
            __builtin_amdgcn_s_setprio(1);
#pragma unroll
            for (int ks = 0; ks < 2; ++ks)
#pragma unroll
                for (int db = 0; db < 8; ++db) {
                    const int d = db * 16 + fro;
                    short8 vf = *(const short8*)&Vs[cur][d * 64 + 8 * ((ks * 4 + fk) ^ (d & 7))];
                    o[db] = __builtin_amdgcn_mfma_f32_16x16x32_bf16(pa[ks], vf, o[db], 0, 0, 0);
                }
            __builtin_amdgcn_s_setprio(0);
            // end-of-tile barrier: protects buf[cur^1] from next iteration's DMA issue.
            __builtin_amdgcn_s_barrier();
            cur ^= 1;
        }
        // ---- epilogue: 1/l, sigmoid gate, store bf16 ----
#pragma unroll
        for (int r = 0; r < 4; ++r) {
            const int qrow = q0w + rbase + r;
            float gv = bf2f(qkv[(size_t)(b * T_ + qrow) * NPAD + QKVD + h]);
            float sg = 1.f / (1.f + __expf(-gv));
            float invl = sg / l_r[r];
            unsigned short* orow = ao + (size_t)(b * T_ + qrow) * 2048 + h * 128;
#pragma unroll
            for (int db = 0; db < 8; ++db)
                orow[db * 16 + fro] = f2bf(o[db][r] * invl);
        }
    }
}

extern "C" void kernel_launch(void* const* d_in, const int* in_sizes, int n_in,
                              void* d_out, int out_size, void* d_ws, size_t ws_size,
                              hipStream_t stream) {
    const float* x      = (const float*)d_in[0];
    const float* cosT   = (const float*)d_in[1];
    const float* sinT   = (const float*)d_in[2];
    const float* W_attn = (const float*)d_in[3];
    const float* qw     = (const float*)d_in[4];
    const float* kw     = (const float*)d_in[5];
    const float* W_proj = (const float*)d_in[6];

    char* ws = (char*)d_ws;
    const size_t OFF_XB   = 0;                       // 4096*2048*2   = 16777216
    const size_t OFF_WAB  = 16777216;                // 3200*2048*2   = 13107200
    const size_t OFF_WPB  = 29884416;                // 2048*2048*2   =  8388608
    const size_t OFF_QKV  = 38273024;                // 4096*3200*2   = 26214400
    const size_t OFF_VT   = 64487424;                // 2*4*128*2048*2=  4194304
    const size_t OFF_AO   = 68681728;                // 4096*2048*2   = 16777216
    const size_t NEED     = 85458944;
    if (ws_size < NEED) return;

    unsigned short* xb   = (unsigned short*)(ws + OFF_XB);
    unsigned short* wab  = (unsigned short*)(ws + OFF_WAB);
    unsigned short* wpb  = (unsigned short*)(ws + OFF_WPB);
    unsigned short* qkvb = (unsigned short*)(ws + OFF_QKV);
    unsigned short* vtb  = (unsigned short*)(ws + OFF_VT);
    unsigned short* aob  = (unsigned short*)(ws + OFF_AO);

    k_convert<<<8192, 256, 0, stream>>>(x,      xb,  2097152, 2097152);
    k_convert<<<6400, 256, 0, stream>>>(W_attn, wab, 1581056, 1638400);
    k_convert<<<4096, 256, 0, stream>>>(W_proj, wpb, 1048576, 1048576);
    k_gemm_nt<unsigned short><<<dim3(32, 25), 256, 0, stream>>>(xb, wab, qkvb, 2048, 2048, 2048, NPAD);
    k_normrope<<<20480, 256, 0, stream>>>(qkvb, cosT, sinT, qw, kw);
    k_transposeV<<<dim3(8, 32, 2), 256, 0, stream>>>(qkvb, vtb);
    k_attn<<<512, 256, 0, stream>>>(qkvb, vtb, aob);
    k_gemm_nt<float><<<dim3(32, 16), 256, 0, stream>>>(aob, wpb, (float*)d_out, 2048, 2048, 2048, 2048);
}

// Round 8
// 246.320 us; speedup vs baseline: 1.0822x; 1.0822x over previous
//
#include <hip/hip_runtime.h>

#define T_   2048
#define BB   2
#define CC   2048
#define HH   16
#define GG   4
#define HSS  128
#define QKVD 3072          // (H+2G)*HS
#define NQKV 3088          // + H gate cols
#define NPAD 3200          // padded to 25*128
#define SCALE_ 0.08838834764831845f   // 1/sqrt(128)

typedef __attribute__((ext_vector_type(8))) short  short8;
typedef __attribute__((ext_vector_type(4))) float  f32x4;
typedef __attribute__((ext_vector_type(4))) int    v4i;
typedef __attribute__((ext_vector_type(4))) float  v4f;
typedef __attribute__((ext_vector_type(4))) unsigned short u16x4;

typedef const void __attribute__((address_space(1)))* gas1_t;
typedef void __attribute__((address_space(3)))* as3_t;

__device__ __forceinline__ void gl_lds16(const void* g, void* l) {
    __builtin_amdgcn_global_load_lds((gas1_t)g, (as3_t)l, 16, 0, 0);
}

__device__ __forceinline__ unsigned short f2bf(float f) {
    unsigned u = __float_as_uint(f);
    u += 0x7fffu + ((u >> 16) & 1u);   // RNE
    return (unsigned short)(u >> 16);
}
__device__ __forceinline__ float bf2f(unsigned short h) {
    return __uint_as_float(((unsigned)h) << 16);
}

// ---------------- f32 -> bf16 convert (with optional zero-pad tail) ----------------
__global__ void k_convert(const float* __restrict__ src, unsigned short* __restrict__ dst,
                          int n_src4, int n_dst4) {
    int i = blockIdx.x * blockDim.x + threadIdx.x;
    if (i >= n_dst4) return;
    u16x4 o;
    if (i < n_src4) {
        v4f v = *(const v4f*)(src + (size_t)i * 4);
        o[0] = f2bf(v[0]); o[1] = f2bf(v[1]); o[2] = f2bf(v[2]); o[3] = f2bf(v[3]);
    } else {
        o[0] = 0; o[1] = 0; o[2] = 0; o[3] = 0;
    }
    *(u16x4*)(dst + (size_t)i * 4) = o;
}

// ---------------- 256x256 8-phase NT GEMM (m201 template, plain HIP) --------------
// C[m][n] = sum_k A[m][k]*B[n][k].  512 thr = 8 waves (2M x 4N), BK=64,
// 128KB LDS double-buffered, XOR-swizzled 16B slots (slot ^= row&7),
// per-phase: {ds_read frags | stage 1 half-tile via global_load_lds | 16 MFMA},
// per-tile vmcnt(0)+barrier.  Store masked to gcol<nmax (ragged N).
template <typename OutT>
__launch_bounds__(512, 2)
__global__ void k_gemm8(const unsigned short* __restrict__ A,
                        const unsigned short* __restrict__ Bm,
                        OutT* __restrict__ C,
                        int K, int lda, int ldb, int ldc, int nmax) {
    __shared__ unsigned short As[2][256 * 64];
    __shared__ unsigned short Bs[2][256 * 64];
    const int t = threadIdx.x;
    const int lane = t & 63;
    const int wid  = t >> 6;
    const int wr = wid >> 2, wc = wid & 3;       // wave grid 2M x 4N
    const int bm = blockIdx.x, bn = blockIdx.y;
    const int fro = lane & 15, fk = lane >> 4;

    // staging lane geometry: 1KB call = 8 rows x 128B; source slot pre-swizzled
    const int srow  = lane >> 3;                  // row within 8-row chunk
    const size_t scol = (size_t)(((lane & 7) ^ srow) * 8);

    const unsigned short* Abase = A  + (size_t)(bm * 256) * lda;
    const unsigned short* Bbase = Bm + (size_t)(bn * 256) * ldb;

    f32x4 acc[8][4];
#pragma unroll
    for (int i = 0; i < 8; ++i)
#pragma unroll
        for (int j = 0; j < 4; ++j) acc[i][j] = (f32x4){0.f, 0.f, 0.f, 0.f};

    // prologue: stage K-tile 0 into buf 0 (A h0,h1 + B h0,h1; 2 calls each per wave)
#pragma unroll
    for (int h = 0; h < 2; ++h)
#pragma unroll
        for (int c8 = 0; c8 < 2; ++c8) {
            const int rr = h * 128 + wid * 16 + c8 * 8;
            gl_lds16(Abase + (size_t)(rr + srow) * lda + scol, &As[0][rr * 64]);
            gl_lds16(Bbase + (size_t)(rr + srow) * ldb + scol, &Bs[0][rr * 64]);
        }

    int cur = 0;
    for (int kt = 0; kt < K; kt += 64) {
        // own-wave DMAs for THIS tile landed; barrier covers other waves' shares.
        asm volatile("s_waitcnt vmcnt(0)" ::: "memory");
        __builtin_amdgcn_s_barrier();
        __builtin_amdgcn_sched_barrier(0);
        const bool pf = (kt + 64 < K);
        const int nxt = cur ^ 1;
        const int kn = kt + 64;

        short8 bf_[4][2];
#pragma unroll
        for (int q = 0; q < 4; ++q) {
            // A-frags for this phase's 2 M-rows
            short8 af[2][2];
#pragma unroll
            for (int im = 0; im < 2; ++im)
#pragma unroll
                for (int kk = 0; kk < 2; ++kk) {
                    const int ar = wr * 128 + (q * 2 + im) * 16 + fro;
                    af[im][kk] = *(const short8*)&As[cur][ar * 64 + ((kk * 4 + fk) ^ (ar & 7)) * 8];
                }
            if (q == 0) {   // B-frags for the whole tile (12 ds_reads this phase)
#pragma unroll
                for (int ni = 0; ni < 4; ++ni)
#pragma unroll
                    for (int kk = 0; kk < 2; ++kk) {
                        const int br = wc * 64 + ni * 16 + fro;
                        bf_[ni][kk] = *(const short8*)&Bs[cur][br * 64 + ((kk * 4 + fk) ^ (br & 7)) * 8];
                    }
            }
            // stage one half-tile of next K-tile: q0:A-h0 q1:A-h1 q2:B-h0 q3:B-h1
            if (pf) {
                const int h = q & 1;
#pragma unroll
                for (int c8 = 0; c8 < 2; ++c8) {
                    const int rr = h * 128 + wid * 16 + c8 * 8;
                    if ((q >> 1) == 0)
                        gl_lds16(Abase + (size_t)(rr + srow) * lda + kn + scol, &As[nxt][rr * 64]);
                    else
                        gl_lds16(Bbase + (size_t)(rr + srow) * ldb + kn + scol, &Bs[nxt][rr * 64]);
                }
            }
            __builtin_amdgcn_s_setprio(1);
#pragma unroll
            for (int im = 0; im < 2; ++im)
#pragma unroll
                for (int ni = 0; ni < 4; ++ni)
#pragma unroll
                    for (int kk = 0; kk < 2; ++kk)
                        acc[q * 2 + im][ni] = __builtin_amdgcn_mfma_f32_16x16x32_bf16(
                            af[im][kk], bf_[ni][kk], acc[q * 2 + im][ni], 0, 0, 0);
            __builtin_amdgcn_s_setprio(0);
            __builtin_amdgcn_s_barrier();
        }
        cur ^= 1;
    }

    // epilogue: D layout col=lane&15, row=(lane>>4)*4+r
    const int col16 = lane & 15, rbase = (lane >> 4) * 4;
    const int gr0 = bm * 256 + wr * 128;
    const int gc0 = bn * 256 + wc * 64;
#pragma unroll
    for (int mi = 0; mi < 8; ++mi)
#pragma unroll
        for (int ni = 0; ni < 4; ++ni) {
            const int gcol = gc0 + ni * 16 + col16;
            if (gcol < nmax) {
#pragma unroll
                for (int r = 0; r < 4; ++r) {
                    const int grow = gr0 + mi * 16 + rbase + r;
                    float v = acc[mi][ni][r];
                    if constexpr (sizeof(OutT) == 2)
                        C[(size_t)grow * ldc + gcol] = (OutT)f2bf(v);
                    else
                        C[(size_t)grow * ldc + gcol] = (OutT)v;
                }
            }
        }
}

// ---------------- fused RMSNorm + RoPE, in place on q/k regions of qkv -------------
__global__ void k_normrope(unsigned short* __restrict__ qkv,
                           const float* __restrict__ cosT, const float* __restrict__ sinT,
                           const float* __restrict__ qw, const float* __restrict__ kw) {
    const int lane = threadIdx.x & 63;
    const int row  = blockIdx.x * 4 + (threadIdx.x >> 6);  // 0 .. 4096*20-1
    const int tok  = row / 20;
    const int hh   = row - tok * 20;
    const int tpos = tok & (T_ - 1);
    unsigned short* rp = qkv + (size_t)tok * NPAD + (hh < 16 ? hh * 128 : 2048 + (hh - 16) * 128);
    const float* w = (hh < 16) ? qw : kw;
    float e1 = bf2f(rp[lane]);
    float e2 = bf2f(rp[lane + 64]);
    float ss = e1 * e1 + e2 * e2;
#pragma unroll
    for (int m = 1; m < 64; m <<= 1) ss += __shfl_xor(ss, m);
    float inv = rsqrtf(ss * (1.0f / 128.0f) + 1e-5f);
    float n1 = e1 * inv * w[lane];
    float n2 = e2 * inv * w[lane + 64];
    float c = cosT[tpos * 64 + lane];
    float s = sinT[tpos * 64 + lane];
    rp[lane]      = f2bf(n1 * c - n2 * s);
    rp[lane + 64] = f2bf(n2 * c + n1 * s);
}

// ---------------- V transpose: VT[b][g][d][s] = V[b][s][g][d] ----------------------
__global__ void k_transposeV(const unsigned short* __restrict__ qkv,
                             unsigned short* __restrict__ vt) {
    __shared__ unsigned short tile[64][65];
    const int b = blockIdx.x >> 2, g = blockIdx.x & 3;
    const int s0 = blockIdx.y * 64, d0 = blockIdx.z * 64;
    const int tx = threadIdx.x & 63, ty0 = threadIdx.x >> 6;
    const unsigned short* src = qkv + (size_t)(b * T_ + s0) * NPAD + 2560 + g * 128 + d0;
#pragma unroll
    for (int r = 0; r < 16; ++r) {
        int ty = ty0 * 16 + r;
        tile[ty][tx] = src[(size_t)ty * NPAD + tx];
    }
    __syncthreads();
    unsigned short* dstp = vt + ((size_t)(b * GG + g) * 128 + d0) * T_ + s0;
#pragma unroll
    for (int r = 0; r < 16; ++r) {
        int ty = ty0 * 16 + r;
        dstp[(size_t)ty * T_ + tx] = tile[tx][ty];
    }
}

// ---------------- flash attention + gate (round-5 measured version) ----------------
__launch_bounds__(256, 2)
__global__ void k_attn(const unsigned short* __restrict__ qkv,
                       const unsigned short* __restrict__ vt,
                       unsigned short* __restrict__ ao) {
    __shared__ unsigned short Ks[2][64 * 128];   // [buf][row kv][slot]  16KB each
    __shared__ unsigned short Vs[2][128 * 64];   // [buf][row d ][slot]  16KB each
    __shared__ unsigned short Ps[4][16 * 72];
    const int t = threadIdx.x;
    const int lane = t & 63;
    const int wid  = t >> 6;
    const int id = blockIdx.x;
    const int bg = id & 7;               // -> XCD (round-robin dispatch assumed)
    const int hh = (id >> 3) & 3;
    const int pr = id >> 5;              // 0..15
    const int b = bg >> 2, g = bg & 3, h = g * 4 + hh;
    const int fro = lane & 15, fk = lane >> 4;
    const int rbase = fk * 4;

    const unsigned short* kg0 = qkv + (size_t)(b * T_) * NPAD + 2048 + g * 128;
    const unsigned short* vg0 = vt + (size_t)(b * GG + g) * 128 * T_;

    const int cp0 = wid * 4;
    int cur = 0;

#pragma unroll
    for (int seg = 0; seg < 2; ++seg) {
        const int qt = (seg == 0) ? pr : 31 - pr;
        const int q0w = qt * 64 + wid * 16;

        short8 qf[4];
        const unsigned short* qp = qkv + (size_t)(b * T_ + q0w + fro) * NPAD + h * 128 + fk * 8;
#pragma unroll
        for (int kb = 0; kb < 4; ++kb) qf[kb] = *(const short8*)(qp + kb * 32);

        float m_r[4], l_r[4];
        f32x4 o[8];
#pragma unroll
        for (int r = 0; r < 4; ++r) { m_r[r] = -1e30f; l_r[r] = 0.f; }
#pragma unroll
        for (int d = 0; d < 8; ++d) o[d] = (f32x4){0.f, 0.f, 0.f, 0.f};

        const int nt = qt + 1;

        // prologue: stage tile 0 into buf[cur]
#pragma unroll
        for (int p = 0; p < 4; ++p) {
            const int cp = cp0 + p;
            const int kr = cp * 4 + (lane >> 4);
            const int sK = lane & 15;
            gl_lds16(kg0 + (size_t)kr * NPAD + (size_t)((sK ^ (kr & 7)) * 8), &Ks[cur][cp * 512]);
            const int d  = cp * 8 + (lane >> 3);
            const int sV = lane & 7;
            gl_lds16(vg0 + (size_t)d * T_ + (size_t)((sV ^ (d & 7)) * 8), &Vs[cur][cp * 512]);
        }
        __syncthreads();

        for (int ti = 0; ti < nt; ++ti) {
            if (ti + 1 < nt) {
                const int sn = (ti + 1) * 64;
#pragma unroll
                for (int p = 0; p < 4; ++p) {
                    const int cp = cp0 + p;
                    const int kr = cp * 4 + (lane >> 4);
                    const int sK = lane & 15;
                    gl_lds16(kg0 + (size_t)(sn + kr) * NPAD + (size_t)((sK ^ (kr & 7)) * 8), &Ks[cur ^ 1][cp * 512]);
                    const int d  = cp * 8 + (lane >> 3);
                    const int sV = lane & 7;
                    gl_lds16(vg0 + (size_t)d * T_ + sn + (size_t)((sV ^ (d & 7)) * 8), &Vs[cur ^ 1][cp * 512]);
                }
            }
            // ---- QK^T on buf[cur]: S[16 q][64 kv] ----
            f32x4 sc[4];
#pragma unroll
            for (int jb = 0; jb < 4; ++jb) sc[jb] = (f32x4){0.f, 0.f, 0.f, 0.f};
#pragma unroll
            for (int jb = 0; jb < 4; ++jb) {
                const int kr = jb * 16 + fro;
#pragma unroll
                for (int kb = 0; kb < 4; ++kb) {
                    short8 kf = *(const short8*)&Ks[cur][kr * 128 + 8 * ((kb * 4 + fk) ^ (kr & 7))];
                    sc[jb] = __builtin_amdgcn_mfma_f32_16x16x32_bf16(qf[kb], kf, sc[jb], 0, 0, 0);
                }
            }
            // ---- scale + causal mask (diagonal tile only) ----
            const bool domask = (ti == qt);
#pragma unroll
            for (int jb = 0; jb < 4; ++jb)
#pragma unroll
                for (int r = 0; r < 4; ++r) {
                    float v = sc[jb][r] * SCALE_;
                    if (domask && (jb * 16 + fro) > (wid * 16 + rbase + r)) v = -1e30f;
                    sc[jb][r] = v;
                }
            // ---- online softmax ----
            float mx[4], fs[4], rs[4];
#pragma unroll
            for (int r = 0; r < 4; ++r)
                mx[r] = fmaxf(fmaxf(sc[0][r], sc[1][r]), fmaxf(sc[2][r], sc[3][r]));
#pragma unroll
            for (int msk = 1; msk < 16; msk <<= 1)
#pragma unroll
                for (int r = 0; r < 4; ++r) mx[r] = fmaxf(mx[r], __shfl_xor(mx[r], msk));
#pragma unroll
            for (int r = 0; r < 4; ++r) {
                float mn = fmaxf(m_r[r], mx[r]);
                fs[r] = __expf(m_r[r] - mn);
                m_r[r] = mn;
            }
#pragma unroll
            for (int jb = 0; jb < 4; ++jb)
#pragma unroll
                for (int r = 0; r < 4; ++r) sc[jb][r] = __expf(sc[jb][r] - m_r[r]);
#pragma unroll
            for (int r = 0; r < 4; ++r)
                rs[r] = (sc[0][r] + sc[1][r]) + (sc[2][r] + sc[3][r]);
#pragma unroll
            for (int msk = 1; msk < 16; msk <<= 1)
#pragma unroll
                for (int r = 0; r < 4; ++r) rs[r] += __shfl_xor(rs[r], msk);
#pragma unroll
            for (int r = 0; r < 4; ++r) l_r[r] = l_r[r] * fs[r] + rs[r];
#pragma unroll
            for (int d = 0; d < 8; ++d)
#pragma unroll
                for (int r = 0; r < 4; ++r) o[d][r] *= fs[r];
            // ---- P -> LDS (per-wave transpose to A-layout) ----
            unsigned short* pw = &Ps[wid][0];
#pragma unroll
            for (int jb = 0; jb < 4; ++jb)
#pragma unroll
                for (int r = 0; r < 4; ++r)
                    pw[(rbase + r) * 72 + jb * 16 + fro] = f2bf(sc[jb][r]);
            asm volatile("s_waitcnt lgkmcnt(0)" ::: "memory");
            __builtin_amdgcn_sched_barrier(0);
            short8 pa[2];
#pragma unroll
            for (int ks = 0; ks < 2; ++ks)
                pa[ks] = *(const short8*)&Ps[wid][fro * 72 + ks * 32 + fk * 8];
            // ---- PV on buf[cur] ----
#pragma unroll
            for (int ks = 0; ks < 2; ++ks)
#pragma unroll
                for (int db = 0; db < 8; ++db) {
                    const int d = db * 16 + fro;
                    short8 vf = *(const short8*)&Vs[cur][d * 64 + 8 * ((ks * 4 + fk) ^ (d & 7))];
                    o[db] = __builtin_amdgcn_mfma_f32_16x16x32_bf16(pa[ks], vf, o[db], 0, 0, 0);
                }
            __syncthreads();
            cur ^= 1;
        }
        // ---- epilogue: 1/l, sigmoid gate, store bf16 ----
#pragma unroll
        for (int r = 0; r < 4; ++r) {
            const int qrow = q0w + rbase + r;
            float gv = bf2f(qkv[(size_t)(b * T_ + qrow) * NPAD + QKVD + h]);
            float sg = 1.f / (1.f + __expf(-gv));
            float invl = sg / l_r[r];
            unsigned short* orow = ao + (size_t)(b * T_ + qrow) * 2048 + h * 128;
#pragma unroll
            for (int db = 0; db < 8; ++db)
                orow[db * 16 + fro] = f2bf(o[db][r] * invl);
        }
    }
}

extern "C" void kernel_launch(void* const* d_in, const int* in_sizes, int n_in,
                              void* d_out, int out_size, void* d_ws, size_t ws_size,
                              hipStream_t stream) {
    const float* x      = (const float*)d_in[0];
    const float* cosT   = (const float*)d_in[1];
    const float* sinT   = (const float*)d_in[2];
    const float* W_attn = (const float*)d_in[3];
    const float* qw     = (const float*)d_in[4];
    const float* kw     = (const float*)d_in[5];
    const float* W_proj = (const float*)d_in[6];

    char* ws = (char*)d_ws;
    const size_t OFF_XB   = 0;                       // 4096*2048*2   = 16777216
    const size_t OFF_WAB  = 16777216;                // 3200*2048*2   = 13107200
    const size_t OFF_WPB  = 29884416;                // 2048*2048*2   =  8388608
    const size_t OFF_QKV  = 38273024;                // 4096*3200*2   = 26214400
    const size_t OFF_VT   = 64487424;                // 2*4*128*2048*2=  4194304
    const size_t OFF_AO   = 68681728;                // 4096*2048*2   = 16777216
    const size_t NEED     = 85458944;
    if (ws_size < NEED) return;

    unsigned short* xb   = (unsigned short*)(ws + OFF_XB);
    unsigned short* wab  = (unsigned short*)(ws + OFF_WAB);
    unsigned short* wpb  = (unsigned short*)(ws + OFF_WPB);
    unsigned short* qkvb = (unsigned short*)(ws + OFF_QKV);
    unsigned short* vtb  = (unsigned short*)(ws + OFF_VT);
    unsigned short* aob  = (unsigned short*)(ws + OFF_AO);

    k_convert<<<8192, 256, 0, stream>>>(x,      xb,  2097152, 2097152);
    k_convert<<<6400, 256, 0, stream>>>(W_attn, wab, 1581056, 1638400);
    k_convert<<<4096, 256, 0, stream>>>(W_proj, wpb, 1048576, 1048576);
    // qkv GEMM: 256x256 8-phase; grid (16,13); bn=12 covers ragged cols via store mask
    k_gemm8<unsigned short><<<dim3(16, 13), 512, 0, stream>>>(xb, wab, qkvb, 2048, 2048, 2048, NPAD, NPAD);
    k_normrope<<<20480, 256, 0, stream>>>(qkvb, cosT, sinT, qw, kw);
    k_transposeV<<<dim3(8, 32, 2), 256, 0, stream>>>(qkvb, vtb);
    k_attn<<<512, 256, 0, stream>>>(qkvb, vtb, aob);
    // out-proj -> f32 d_out
    k_gemm8<float><<<dim3(16, 8), 512, 0, stream>>>(aob, wpb, (float*)d_out, 2048, 2048, 2048, 2048, 2048);
}

// Round 9
// 224.408 us; speedup vs baseline: 1.1878x; 1.0976x over previous
//
#include <hip/hip_runtime.h>

#define T_   2048
#define BB   2
#define CC   2048
#define HH   16
#define GG   4
#define HSS  128
#define QKVD 3072          // (H+2G)*HS
#define NQKV 3088          // + H gate cols
#define NPAD 3200          // padded to 25*128
#define SCALE_ 0.08838834764831845f   // 1/sqrt(128)
#define SCALE2_ (0.08838834764831845f * 1.4426950408889634f)   // 1/sqrt(128) * log2(e)

typedef __attribute__((ext_vector_type(8))) short  short8;
typedef __attribute__((ext_vector_type(4))) float  f32x4;
typedef __attribute__((ext_vector_type(4))) int    v4i;
typedef __attribute__((ext_vector_type(4))) float  v4f;
typedef __attribute__((ext_vector_type(4))) unsigned short u16x4;

typedef const void __attribute__((address_space(1)))* gas1_t;
typedef void __attribute__((address_space(3)))* as3_t;

__device__ __forceinline__ void gl_lds16(const void* g, void* l) {
    __builtin_amdgcn_global_load_lds((gas1_t)g, (as3_t)l, 16, 0, 0);
}

__device__ __forceinline__ unsigned short f2bf(float f) {
    unsigned u = __float_as_uint(f);
    u += 0x7fffu + ((u >> 16) & 1u);   // RNE
    return (unsigned short)(u >> 16);
}
__device__ __forceinline__ float bf2f(unsigned short h) {
    return __uint_as_float(((unsigned)h) << 16);
}

// DPP cross-lane move within a 16-lane row (full-rate VALU, no LDS pipe).
// quad_perm xor1 = 0xB1, xor2 = 0x4E, row_ror:4 = 0x124, row_ror:8 = 0x128.
template <int CTRL>
__device__ __forceinline__ float dppmv(float x) {
    int i = __float_as_int(x);
    return __int_as_float(__builtin_amdgcn_update_dpp(i, i, CTRL, 0xF, 0xF, false));
}
__device__ __forceinline__ void red16_max(float* v) {
#pragma unroll
    for (int r = 0; r < 4; ++r) v[r] = fmaxf(v[r], dppmv<0xB1>(v[r]));
#pragma unroll
    for (int r = 0; r < 4; ++r) v[r] = fmaxf(v[r], dppmv<0x4E>(v[r]));
#pragma unroll
    for (int r = 0; r < 4; ++r) v[r] = fmaxf(v[r], dppmv<0x124>(v[r]));
#pragma unroll
    for (int r = 0; r < 4; ++r) v[r] = fmaxf(v[r], dppmv<0x128>(v[r]));
}
__device__ __forceinline__ void red16_sum(float* v) {
#pragma unroll
    for (int r = 0; r < 4; ++r) v[r] += dppmv<0xB1>(v[r]);
#pragma unroll
    for (int r = 0; r < 4; ++r) v[r] += dppmv<0x4E>(v[r]);
#pragma unroll
    for (int r = 0; r < 4; ++r) v[r] += dppmv<0x124>(v[r]);
#pragma unroll
    for (int r = 0; r < 4; ++r) v[r] += dppmv<0x128>(v[r]);
}

// ---------------- f32 -> bf16 convert (with optional zero-pad tail) ----------------
__global__ void k_convert(const float* __restrict__ src, unsigned short* __restrict__ dst,
                          int n_src4, int n_dst4) {
    int i = blockIdx.x * blockDim.x + threadIdx.x;
    if (i >= n_dst4) return;
    u16x4 o;
    if (i < n_src4) {
        v4f v = *(const v4f*)(src + (size_t)i * 4);
        o[0] = f2bf(v[0]); o[1] = f2bf(v[1]); o[2] = f2bf(v[2]); o[3] = f2bf(v[3]);
    } else {
        o[0] = 0; o[1] = 0; o[2] = 0; o[3] = 0;
    }
    *(u16x4*)(dst + (size_t)i * 4) = o;
}

// ---------------- BM_x256 8-phase NT GEMM (m201 template, plain HIP) --------------
// C[m][n] = sum_k A[m][k]*B[n][k].  512 thr = 8 waves (2M x 4N), BK=64,
// double-buffered LDS, XOR-swizzled 16B slots (slot ^= row&7),
// per-phase: {ds_read frags | stage via global_load_lds | 16 MFMA},
// per-tile vmcnt(0)+barrier.  BM_ in {256,128}; store masked to gcol<nmax.
template <int BM_, typename OutT>
__launch_bounds__(512, 2)
__global__ void k_gemm8(const unsigned short* __restrict__ A,
                        const unsigned short* __restrict__ Bm,
                        OutT* __restrict__ C,
                        int K, int lda, int ldb, int ldc, int nmax) {
    constexpr int MI  = BM_ / 32;     // M-frags per wave (8 or 4)
    constexpr int NPH = MI / 2;       // phases per K-tile (4 or 2), 2 mi per phase
    __shared__ unsigned short As[2][BM_ * 64];
    __shared__ unsigned short Bs[2][256 * 64];
    const int t = threadIdx.x;
    const int lane = t & 63;
    const int wid  = t >> 6;
    const int wr = wid >> 2, wc = wid & 3;       // wave grid 2M x 4N
    const int bm = blockIdx.x, bn = blockIdx.y;
    const int fro = lane & 15, fk = lane >> 4;

    const int srow  = lane >> 3;                  // row within 8-row chunk
    const size_t scol = (size_t)(((lane & 7) ^ srow) * 8);

    const unsigned short* Abase = A  + (size_t)(bm * BM_) * lda;
    const unsigned short* Bbase = Bm + (size_t)(bn * 256) * ldb;

    f32x4 acc[MI][4];
#pragma unroll
    for (int i = 0; i < MI; ++i)
#pragma unroll
        for (int j = 0; j < 4; ++j) acc[i][j] = (f32x4){0.f, 0.f, 0.f, 0.f};

    // prologue: stage K-tile 0 into buf 0 (full A + full B)
#pragma unroll
    for (int h = 0; h < 2; ++h)
#pragma unroll
        for (int c8 = 0; c8 < 2; ++c8) {
            const int rr = h * 128 + wid * 16 + c8 * 8;
            if (BM_ == 256 || h == 0)
                gl_lds16(Abase + (size_t)(rr + srow) * lda + scol, &As[0][rr * 64]);
            gl_lds16(Bbase + (size_t)(rr + srow) * ldb + scol, &Bs[0][rr * 64]);
        }

    int cur = 0;
    for (int kt = 0; kt < K; kt += 64) {
        asm volatile("s_waitcnt vmcnt(0)" ::: "memory");
        __builtin_amdgcn_s_barrier();
        __builtin_amdgcn_sched_barrier(0);
        const bool pf = (kt + 64 < K);
        const int nxt = cur ^ 1;
        const int kn = kt + 64;

        short8 bf_[4][2];
#pragma unroll
        for (int q = 0; q < NPH; ++q) {
            // A-frags for this phase's 2 M-rows
            short8 af[2][2];
#pragma unroll
            for (int im = 0; im < 2; ++im)
#pragma unroll
                for (int kk = 0; kk < 2; ++kk) {
                    const int ar = wr * (BM_ / 2) + (q * 2 + im) * 16 + fro;
                    af[im][kk] = *(const short8*)&As[cur][ar * 64 + ((kk * 4 + fk) ^ (ar & 7)) * 8];
                }
            if (q == 0) {   // B-frags for the whole tile
#pragma unroll
                for (int ni = 0; ni < 4; ++ni)
#pragma unroll
                    for (int kk = 0; kk < 2; ++kk) {
                        const int br = wc * 64 + ni * 16 + fro;
                        bf_[ni][kk] = *(const short8*)&Bs[cur][br * 64 + ((kk * 4 + fk) ^ (br & 7)) * 8];
                    }
            }
            // stage next K-tile
            if (pf) {
                if (BM_ == 256) {
                    // q0:A-h0 q1:A-h1 q2:B-h0 q3:B-h1
                    const int h = q & 1;
#pragma unroll
                    for (int c8 = 0; c8 < 2; ++c8) {
                        const int rr = h * 128 + wid * 16 + c8 * 8;
                        if ((q >> 1) == 0)
                            gl_lds16(Abase + (size_t)(rr + srow) * lda + kn + scol, &As[nxt][rr * 64]);
                        else
                            gl_lds16(Bbase + (size_t)(rr + srow) * ldb + kn + scol, &Bs[nxt][rr * 64]);
                    }
                } else {
                    // q0: A (2 calls), q1: B (4 calls)
                    if (q == 0) {
#pragma unroll
                        for (int c8 = 0; c8 < 2; ++c8) {
                            const int rr = wid * 16 + c8 * 8;
                            gl_lds16(Abase + (size_t)(rr + srow) * lda + kn + scol, &As[nxt][rr * 64]);
                        }
                    } else {
#pragma unroll
                        for (int h = 0; h < 2; ++h)
#pragma unroll
                            for (int c8 = 0; c8 < 2; ++c8) {
                                const int rr = h * 128 + wid * 16 + c8 * 8;
                                gl_lds16(Bbase + (size_t)(rr + srow) * ldb + kn + scol, &Bs[nxt][rr * 64]);
                            }
                    }
                }
            }
            __builtin_amdgcn_s_setprio(1);
#pragma unroll
            for (int im = 0; im < 2; ++im)
#pragma unroll
                for (int ni = 0; ni < 4; ++ni)
#pragma unroll
                    for (int kk = 0; kk < 2; ++kk)
                        acc[q * 2 + im][ni] = __builtin_amdgcn_mfma_f32_16x16x32_bf16(
                            af[im][kk], bf_[ni][kk], acc[q * 2 + im][ni], 0, 0, 0);
            __builtin_amdgcn_s_setprio(0);
            __builtin_amdgcn_s_barrier();
        }
        cur ^= 1;
    }

    // epilogue: D layout col=lane&15, row=(lane>>4)*4+r
    const int col16 = lane & 15, rbase = (lane >> 4) * 4;
    const int gr0 = bm * BM_ + wr * (BM_ / 2);
    const int gc0 = bn * 256 + wc * 64;
#pragma unroll
    for (int mi = 0; mi < MI; ++mi)
#pragma unroll
        for (int ni = 0; ni < 4; ++ni) {
            const int gcol = gc0 + ni * 16 + col16;
            if (gcol < nmax) {
#pragma unroll
                for (int r = 0; r < 4; ++r) {
                    const int grow = gr0 + mi * 16 + rbase + r;
                    float v = acc[mi][ni][r];
                    if constexpr (sizeof(OutT) == 2)
                        C[(size_t)grow * ldc + gcol] = (OutT)f2bf(v);
                    else
                        C[(size_t)grow * ldc + gcol] = (OutT)v;
                }
            }
        }
}

// ---------------- fused RMSNorm + RoPE, in place on q/k regions of qkv -------------
__global__ void k_normrope(unsigned short* __restrict__ qkv,
                           const float* __restrict__ cosT, const float* __restrict__ sinT,
                           const float* __restrict__ qw, const float* __restrict__ kw) {
    const int lane = threadIdx.x & 63;
    const int row  = blockIdx.x * 4 + (threadIdx.x >> 6);  // 0 .. 4096*20-1
    const int tok  = row / 20;
    const int hh   = row - tok * 20;
    const int tpos = tok & (T_ - 1);
    unsigned short* rp = qkv + (size_t)tok * NPAD + (hh < 16 ? hh * 128 : 2048 + (hh - 16) * 128);
    const float* w = (hh < 16) ? qw : kw;
    float e1 = bf2f(rp[lane]);
    float e2 = bf2f(rp[lane + 64]);
    float ss = e1 * e1 + e2 * e2;
#pragma unroll
    for (int m = 1; m < 64; m <<= 1) ss += __shfl_xor(ss, m);
    float inv = rsqrtf(ss * (1.0f / 128.0f) + 1e-5f);
    float n1 = e1 * inv * w[lane];
    float n2 = e2 * inv * w[lane + 64];
    float c = cosT[tpos * 64 + lane];
    float s = sinT[tpos * 64 + lane];
    rp[lane]      = f2bf(n1 * c - n2 * s);
    rp[lane + 64] = f2bf(n2 * c + n1 * s);
}

// ---------------- V transpose: VT[b][g][d][s] = V[b][s][g][d] ----------------------
__global__ void k_transposeV(const unsigned short* __restrict__ qkv,
                             unsigned short* __restrict__ vt) {
    __shared__ unsigned short tile[64][65];
    const int b = blockIdx.x >> 2, g = blockIdx.x & 3;
    const int s0 = blockIdx.y * 64, d0 = blockIdx.z * 64;
    const int tx = threadIdx.x & 63, ty0 = threadIdx.x >> 6;
    const unsigned short* src = qkv + (size_t)(b * T_ + s0) * NPAD + 2560 + g * 128 + d0;
#pragma unroll
    for (int r = 0; r < 16; ++r) {
        int ty = ty0 * 16 + r;
        tile[ty][tx] = src[(size_t)ty * NPAD + tx];
    }
    __syncthreads();
    unsigned short* dstp = vt + ((size_t)(b * GG + g) * 128 + d0) * T_ + s0;
#pragma unroll
    for (int r = 0; r < 16; ++r) {
        int ty = ty0 * 16 + r;
        dstp[(size_t)ty * T_ + tx] = tile[tx][ty];
    }
}

// ---------------- flash attention + gate (round-5 structure + DPP + exp2) ----------
__launch_bounds__(256, 2)
__global__ void k_attn(const unsigned short* __restrict__ qkv,
                       const unsigned short* __restrict__ vt,
                       unsigned short* __restrict__ ao) {
    __shared__ unsigned short Ks[2][64 * 128];   // [buf][row kv][slot]  16KB each
    __shared__ unsigned short Vs[2][128 * 64];   // [buf][row d ][slot]  16KB each
    __shared__ unsigned short Ps[4][16 * 72];
    const int t = threadIdx.x;
    const int lane = t & 63;
    const int wid  = t >> 6;
    const int id = blockIdx.x;
    const int bg = id & 7;               // -> XCD (round-robin dispatch assumed)
    const int hh = (id >> 3) & 3;
    const int pr = id >> 5;              // 0..15
    const int b = bg >> 2, g = bg & 3, h = g * 4 + hh;
    const int fro = lane & 15, fk = lane >> 4;
    const int rbase = fk * 4;

    const unsigned short* kg0 = qkv + (size_t)(b * T_) * NPAD + 2048 + g * 128;
    const unsigned short* vg0 = vt + (size_t)(b * GG + g) * 128 * T_;

    const int cp0 = wid * 4;
    int cur = 0;

#pragma unroll
    for (int seg = 0; seg < 2; ++seg) {
        const int qt = (seg == 0) ? pr : 31 - pr;
        const int q0w = qt * 64 + wid * 16;

        short8 qf[4];
        const unsigned short* qp = qkv + (size_t)(b * T_ + q0w + fro) * NPAD + h * 128 + fk * 8;
#pragma unroll
        for (int kb = 0; kb < 4; ++kb) qf[kb] = *(const short8*)(qp + kb * 32);

        float m_r[4], l_r[4];
        f32x4 o[8];
#pragma unroll
        for (int r = 0; r < 4; ++r) { m_r[r] = -1e30f; l_r[r] = 0.f; }
#pragma unroll
        for (int d = 0; d < 8; ++d) o[d] = (f32x4){0.f, 0.f, 0.f, 0.f};

        const int nt = qt + 1;

        // prologue: stage tile 0 into buf[cur]
#pragma unroll
        for (int p = 0; p < 4; ++p) {
            const int cp = cp0 + p;
            const int kr = cp * 4 + (lane >> 4);
            const int sK = lane & 15;
            gl_lds16(kg0 + (size_t)kr * NPAD + (size_t)((sK ^ (kr & 7)) * 8), &Ks[cur][cp * 512]);
            const int d  = cp * 8 + (lane >> 3);
            const int sV = lane & 7;
            gl_lds16(vg0 + (size_t)d * T_ + (size_t)((sV ^ (d & 7)) * 8), &Vs[cur][cp * 512]);
        }
        __syncthreads();

        for (int ti = 0; ti < nt; ++ti) {
            if (ti + 1 < nt) {
                const int sn = (ti + 1) * 64;
#pragma unroll
                for (int p = 0; p < 4; ++p) {
                    const int cp = cp0 + p;
                    const int kr = cp * 4 + (lane >> 4);
                    const int sK = lane & 15;
                    gl_lds16(kg0 + (size_t)(sn + kr) * NPAD + (size_t)((sK ^ (kr & 7)) * 8), &Ks[cur ^ 1][cp * 512]);
                    const int d  = cp * 8 + (lane >> 3);
                    const int sV = lane & 7;
                    gl_lds16(vg0 + (size_t)d * T_ + sn + (size_t)((sV ^ (d & 7)) * 8), &Vs[cur ^ 1][cp * 512]);
                }
            }
            // ---- QK^T on buf[cur]: S[16 q][64 kv] ----
            f32x4 sc[4];
#pragma unroll
            for (int jb = 0; jb < 4; ++jb) sc[jb] = (f32x4){0.f, 0.f, 0.f, 0.f};
#pragma unroll
            for (int jb = 0; jb < 4; ++jb) {
                const int kr = jb * 16 + fro;
#pragma unroll
                for (int kb = 0; kb < 4; ++kb) {
                    short8 kf = *(const short8*)&Ks[cur][kr * 128 + 8 * ((kb * 4 + fk) ^ (kr & 7))];
                    sc[jb] = __builtin_amdgcn_mfma_f32_16x16x32_bf16(qf[kb], kf, sc[jb], 0, 0, 0);
                }
            }
            // ---- scale (log2 domain) + causal mask (diagonal tile only) ----
            const bool domask = (ti == qt);
#pragma unroll
            for (int jb = 0; jb < 4; ++jb)
#pragma unroll
                for (int r = 0; r < 4; ++r) {
                    float v = sc[jb][r] * SCALE2_;
                    if (domask && (jb * 16 + fro) > (wid * 16 + rbase + r)) v = -1e30f;
                    sc[jb][r] = v;
                }
            // ---- online softmax (DPP 16-lane reductions) ----
            float mx[4], fs[4], rs[4];
#pragma unroll
            for (int r = 0; r < 4; ++r)
                mx[r] = fmaxf(fmaxf(sc[0][r], sc[1][r]), fmaxf(sc[2][r], sc[3][r]));
            red16_max(mx);
#pragma unroll
            for (int r = 0; r < 4; ++r) {
                float mn = fmaxf(m_r[r], mx[r]);
                fs[r] = exp2f(m_r[r] - mn);
                m_r[r] = mn;
            }
#pragma unroll
            for (int jb = 0; jb < 4; ++jb)
#pragma unroll
                for (int r = 0; r < 4; ++r) sc[jb][r] = exp2f(sc[jb][r] - m_r[r]);
#pragma unroll
            for (int r = 0; r < 4; ++r)
                rs[r] = (sc[0][r] + sc[1][r]) + (sc[2][r] + sc[3][r]);
            red16_sum(rs);
#pragma unroll
            for (int r = 0; r < 4; ++r) l_r[r] = l_r[r] * fs[r] + rs[r];
#pragma unroll
            for (int d = 0; d < 8; ++d)
#pragma unroll
                for (int r = 0; r < 4; ++r) o[d][r] *= fs[r];
            // ---- P -> LDS (per-wave transpose to A-layout) ----
            unsigned short* pw = &Ps[wid][0];
#pragma unroll
            for (int jb = 0; jb < 4; ++jb)
#pragma unroll
                for (int r = 0; r < 4; ++r)
                    pw[(rbase + r) * 72 + jb * 16 + fro] = f2bf(sc[jb][r]);
            asm volatile("s_waitcnt lgkmcnt(0)" ::: "memory");
            __builtin_amdgcn_sched_barrier(0);
            short8 pa[2];
#pragma unroll
            for (int ks = 0; ks < 2; ++ks)
                pa[ks] = *(const short8*)&Ps[wid][fro * 72 + ks * 32 + fk * 8];
            // ---- PV on buf[cur] ----
#pragma unroll
            for (int ks = 0; ks < 2; ++ks)
#pragma unroll
                for (int db = 0; db < 8; ++db) {
                    const int d = db * 16 + fro;
                    short8 vf = *(const short8*)&Vs[cur][d * 64 + 8 * ((ks * 4 + fk) ^ (d & 7))];
                    o[db] = __builtin_amdgcn_mfma_f32_16x16x32_bf16(pa[ks], vf, o[db], 0, 0, 0);
                }
            __syncthreads();
            cur ^= 1;
        }
        // ---- epilogue: 1/l, sigmoid gate, store bf16 ----
#pragma unroll
        for (int r = 0; r < 4; ++r) {
            const int qrow = q0w + rbase + r;
            float gv = bf2f(qkv[(size_t)(b * T_ + qrow) * NPAD + QKVD + h]);
            float sg = 1.f / (1.f + __expf(-gv));
            float invl = sg / l_r[r];
            unsigned short* orow = ao + (size_t)(b * T_ + qrow) * 2048 + h * 128;
#pragma unroll
            for (int db = 0; db < 8; ++db)
                orow[db * 16 + fro] = f2bf(o[db][r] * invl);
        }
    }
}

extern "C" void kernel_launch(void* const* d_in, const int* in_sizes, int n_in,
                              void* d_out, int out_size, void* d_ws, size_t ws_size,
                              hipStream_t stream) {
    const float* x      = (const float*)d_in[0];
    const float* cosT   = (const float*)d_in[1];
    const float* sinT   = (const float*)d_in[2];
    const float* W_attn = (const float*)d_in[3];
    const float* qw     = (const float*)d_in[4];
    const float* kw     = (const float*)d_in[5];
    const float* W_proj = (const float*)d_in[6];

    char* ws = (char*)d_ws;
    const size_t OFF_XB   = 0;                       // 4096*2048*2   = 16777216
    const size_t OFF_WAB  = 16777216;                // 3200*2048*2   = 13107200
    const size_t OFF_WPB  = 29884416;                // 2048*2048*2   =  8388608
    const size_t OFF_QKV  = 38273024;                // 4096*3200*2   = 26214400
    const size_t OFF_VT   = 64487424;                // 2*4*128*2048*2=  4194304
    const size_t OFF_AO   = 68681728;                // 4096*2048*2   = 16777216
    const size_t NEED     = 85458944;
    if (ws_size < NEED) return;

    unsigned short* xb   = (unsigned short*)(ws + OFF_XB);
    unsigned short* wab  = (unsigned short*)(ws + OFF_WAB);
    unsigned short* wpb  = (unsigned short*)(ws + OFF_WPB);
    unsigned short* qkvb = (unsigned short*)(ws + OFF_QKV);
    unsigned short* vtb  = (unsigned short*)(ws + OFF_VT);
    unsigned short* aob  = (unsigned short*)(ws + OFF_AO);

    k_convert<<<8192, 256, 0, stream>>>(x,      xb,  2097152, 2097152);
    k_convert<<<6400, 256, 0, stream>>>(W_attn, wab, 1581056, 1638400);
    k_convert<<<4096, 256, 0, stream>>>(W_proj, wpb, 1048576, 1048576);
    // qkv GEMM: 256x256 8-phase; grid (16,13); bn=12 covers ragged cols via store mask
    k_gemm8<256, unsigned short><<<dim3(16, 13), 512, 0, stream>>>(xb, wab, qkvb, 2048, 2048, 2048, NPAD, NPAD);
    k_normrope<<<20480, 256, 0, stream>>>(qkvb, cosT, sinT, qw, kw);
    k_transposeV<<<dim3(8, 32, 2), 256, 0, stream>>>(qkvb, vtb);
    k_attn<<<512, 256, 0, stream>>>(qkvb, vtb, aob);
    // out-proj: 128x256 tiles -> grid (32,8) = 256 blocks (full CU coverage)
    k_gemm8<128, float><<<dim3(32, 8), 512, 0, stream>>>(aob, wpb, (float*)d_out, 2048, 2048, 2048, 2048, 2048);
}

// Round 10
// 219.508 us; speedup vs baseline: 1.2144x; 1.0223x over previous
//
#include <hip/hip_runtime.h>

#define T_   2048
#define BB   2
#define CC   2048
#define HH   16
#define GG   4
#define HSS  128
#define QKVD 3072          // (H+2G)*HS
#define NQKV 3088          // + H gate cols
#define NPAD 3200          // padded to 25*128
#define SCALE_ 0.08838834764831845f   // 1/sqrt(128)
#define SCALE2_ (0.08838834764831845f * 1.4426950408889634f)   // 1/sqrt(128) * log2(e)

typedef __attribute__((ext_vector_type(8))) short  short8;
typedef __attribute__((ext_vector_type(4))) float  f32x4;
typedef __attribute__((ext_vector_type(4))) int    v4i;
typedef __attribute__((ext_vector_type(4))) float  v4f;
typedef __attribute__((ext_vector_type(4))) unsigned short u16x4;

typedef const void __attribute__((address_space(1)))* gas1_t;
typedef void __attribute__((address_space(3)))* as3_t;

__device__ __forceinline__ void gl_lds16(const void* g, void* l) {
    __builtin_amdgcn_global_load_lds((gas1_t)g, (as3_t)l, 16, 0, 0);
}

__device__ __forceinline__ unsigned short f2bf(float f) {
    unsigned u = __float_as_uint(f);
    u += 0x7fffu + ((u >> 16) & 1u);   // RNE
    return (unsigned short)(u >> 16);
}
__device__ __forceinline__ float bf2f(unsigned short h) {
    return __uint_as_float(((unsigned)h) << 16);
}

// DPP cross-lane move within a 16-lane row (full-rate VALU, no LDS pipe).
template <int CTRL>
__device__ __forceinline__ float dppmv(float x) {
    int i = __float_as_int(x);
    return __int_as_float(__builtin_amdgcn_update_dpp(i, i, CTRL, 0xF, 0xF, false));
}
__device__ __forceinline__ void red16_max(float* v) {
#pragma unroll
    for (int r = 0; r < 4; ++r) v[r] = fmaxf(v[r], dppmv<0xB1>(v[r]));
#pragma unroll
    for (int r = 0; r < 4; ++r) v[r] = fmaxf(v[r], dppmv<0x4E>(v[r]));
#pragma unroll
    for (int r = 0; r < 4; ++r) v[r] = fmaxf(v[r], dppmv<0x124>(v[r]));
#pragma unroll
    for (int r = 0; r < 4; ++r) v[r] = fmaxf(v[r], dppmv<0x128>(v[r]));
}
__device__ __forceinline__ void red16_sum(float* v) {
#pragma unroll
    for (int r = 0; r < 4; ++r) v[r] += dppmv<0xB1>(v[r]);
#pragma unroll
    for (int r = 0; r < 4; ++r) v[r] += dppmv<0x4E>(v[r]);
#pragma unroll
    for (int r = 0; r < 4; ++r) v[r] += dppmv<0x124>(v[r]);
#pragma unroll
    for (int r = 0; r < 4; ++r) v[r] += dppmv<0x128>(v[r]);
}

// ---------------- f32 -> bf16 convert (with optional zero-pad tail) ----------------
__global__ void k_convert(const float* __restrict__ src, unsigned short* __restrict__ dst,
                          int n_src4, int n_dst4) {
    int i = blockIdx.x * blockDim.x + threadIdx.x;
    if (i >= n_dst4) return;
    u16x4 o;
    if (i < n_src4) {
        v4f v = *(const v4f*)(src + (size_t)i * 4);
        o[0] = f2bf(v[0]); o[1] = f2bf(v[1]); o[2] = f2bf(v[2]); o[3] = f2bf(v[3]);
    } else {
        o[0] = 0; o[1] = 0; o[2] = 0; o[3] = 0;
    }
    *(u16x4*)(dst + (size_t)i * 4) = o;
}

// ---------------- BM_x256 8-phase NT GEMM (m201 template, plain HIP) --------------
template <int BM_, typename OutT>
__launch_bounds__(512, 2)
__global__ void k_gemm8(const unsigned short* __restrict__ A,
                        const unsigned short* __restrict__ Bm,
                        OutT* __restrict__ C,
                        int K, int lda, int ldb, int ldc, int nmax) {
    constexpr int MI  = BM_ / 32;     // M-frags per wave (8 or 4)
    constexpr int NPH = MI / 2;       // phases per K-tile (4 or 2)
    __shared__ unsigned short As[2][BM_ * 64];
    __shared__ unsigned short Bs[2][256 * 64];
    const int t = threadIdx.x;
    const int lane = t & 63;
    const int wid  = t >> 6;
    const int wr = wid >> 2, wc = wid & 3;       // wave grid 2M x 4N
    const int bm = blockIdx.x, bn = blockIdx.y;
    const int fro = lane & 15, fk = lane >> 4;

    const int srow  = lane >> 3;
    const size_t scol = (size_t)(((lane & 7) ^ srow) * 8);

    const unsigned short* Abase = A  + (size_t)(bm * BM_) * lda;
    const unsigned short* Bbase = Bm + (size_t)(bn * 256) * ldb;

    f32x4 acc[MI][4];
#pragma unroll
    for (int i = 0; i < MI; ++i)
#pragma unroll
        for (int j = 0; j < 4; ++j) acc[i][j] = (f32x4){0.f, 0.f, 0.f, 0.f};

#pragma unroll
    for (int h = 0; h < 2; ++h)
#pragma unroll
        for (int c8 = 0; c8 < 2; ++c8) {
            const int rr = h * 128 + wid * 16 + c8 * 8;
            if (BM_ == 256 || h == 0)
                gl_lds16(Abase + (size_t)(rr + srow) * lda + scol, &As[0][rr * 64]);
            gl_lds16(Bbase + (size_t)(rr + srow) * ldb + scol, &Bs[0][rr * 64]);
        }

    int cur = 0;
    for (int kt = 0; kt < K; kt += 64) {
        asm volatile("s_waitcnt vmcnt(0)" ::: "memory");
        __builtin_amdgcn_s_barrier();
        __builtin_amdgcn_sched_barrier(0);
        const bool pf = (kt + 64 < K);
        const int nxt = cur ^ 1;
        const int kn = kt + 64;

        short8 bf_[4][2];
#pragma unroll
        for (int q = 0; q < NPH; ++q) {
            short8 af[2][2];
#pragma unroll
            for (int im = 0; im < 2; ++im)
#pragma unroll
                for (int kk = 0; kk < 2; ++kk) {
                    const int ar = wr * (BM_ / 2) + (q * 2 + im) * 16 + fro;
                    af[im][kk] = *(const short8*)&As[cur][ar * 64 + ((kk * 4 + fk) ^ (ar & 7)) * 8];
                }
            if (q == 0) {
#pragma unroll
                for (int ni = 0; ni < 4; ++ni)
#pragma unroll
                    for (int kk = 0; kk < 2; ++kk) {
                        const int br = wc * 64 + ni * 16 + fro;
                        bf_[ni][kk] = *(const short8*)&Bs[cur][br * 64 + ((kk * 4 + fk) ^ (br & 7)) * 8];
                    }
            }
            if (pf) {
                if (BM_ == 256) {
                    const int h = q & 1;
#pragma unroll
                    for (int c8 = 0; c8 < 2; ++c8) {
                        const int rr = h * 128 + wid * 16 + c8 * 8;
                        if ((q >> 1) == 0)
                            gl_lds16(Abase + (size_t)(rr + srow) * lda + kn + scol, &As[nxt][rr * 64]);
                        else
                            gl_lds16(Bbase + (size_t)(rr + srow) * ldb + kn + scol, &Bs[nxt][rr * 64]);
                    }
                } else {
                    if (q == 0) {
#pragma unroll
                        for (int c8 = 0; c8 < 2; ++c8) {
                            const int rr = wid * 16 + c8 * 8;
                            gl_lds16(Abase + (size_t)(rr + srow) * lda + kn + scol, &As[nxt][rr * 64]);
                        }
                    } else {
#pragma unroll
                        for (int h = 0; h < 2; ++h)
#pragma unroll
                            for (int c8 = 0; c8 < 2; ++c8) {
                                const int rr = h * 128 + wid * 16 + c8 * 8;
                                gl_lds16(Bbase + (size_t)(rr + srow) * ldb + kn + scol, &Bs[nxt][rr * 64]);
                            }
                    }
                }
            }
            __builtin_amdgcn_s_setprio(1);
#pragma unroll
            for (int im = 0; im < 2; ++im)
#pragma unroll
                for (int ni = 0; ni < 4; ++ni)
#pragma unroll
                    for (int kk = 0; kk < 2; ++kk)
                        acc[q * 2 + im][ni] = __builtin_amdgcn_mfma_f32_16x16x32_bf16(
                            af[im][kk], bf_[ni][kk], acc[q * 2 + im][ni], 0, 0, 0);
            __builtin_amdgcn_s_setprio(0);
            __builtin_amdgcn_s_barrier();
        }
        cur ^= 1;
    }

    const int col16 = lane & 15, rbase = (lane >> 4) * 4;
    const int gr0 = bm * BM_ + wr * (BM_ / 2);
    const int gc0 = bn * 256 + wc * 64;
#pragma unroll
    for (int mi = 0; mi < MI; ++mi)
#pragma unroll
        for (int ni = 0; ni < 4; ++ni) {
            const int gcol = gc0 + ni * 16 + col16;
            if (gcol < nmax) {
#pragma unroll
                for (int r = 0; r < 4; ++r) {
                    const int grow = gr0 + mi * 16 + rbase + r;
                    float v = acc[mi][ni][r];
                    if constexpr (sizeof(OutT) == 2)
                        C[(size_t)grow * ldc + gcol] = (OutT)f2bf(v);
                    else
                        C[(size_t)grow * ldc + gcol] = (OutT)v;
                }
            }
        }
}

// ---------------- fused RMSNorm + RoPE, in place on q/k regions of qkv -------------
__global__ void k_normrope(unsigned short* __restrict__ qkv,
                           const float* __restrict__ cosT, const float* __restrict__ sinT,
                           const float* __restrict__ qw, const float* __restrict__ kw) {
    const int lane = threadIdx.x & 63;
    const int row  = blockIdx.x * 4 + (threadIdx.x >> 6);  // 0 .. 4096*20-1
    const int tok  = row / 20;
    const int hh   = row - tok * 20;
    const int tpos = tok & (T_ - 1);
    unsigned short* rp = qkv + (size_t)tok * NPAD + (hh < 16 ? hh * 128 : 2048 + (hh - 16) * 128);
    const float* w = (hh < 16) ? qw : kw;
    float e1 = bf2f(rp[lane]);
    float e2 = bf2f(rp[lane + 64]);
    float ss = e1 * e1 + e2 * e2;
#pragma unroll
    for (int m = 1; m < 64; m <<= 1) ss += __shfl_xor(ss, m);
    float inv = rsqrtf(ss * (1.0f / 128.0f) + 1e-5f);
    float n1 = e1 * inv * w[lane];
    float n2 = e2 * inv * w[lane + 64];
    float c = cosT[tpos * 64 + lane];
    float s = sinT[tpos * 64 + lane];
    rp[lane]      = f2bf(n1 * c - n2 * s);
    rp[lane + 64] = f2bf(n2 * c + n1 * s);
}

// ---------------- V transpose: VT[b][g][d][s] = V[b][s][g][d] ----------------------
__global__ void k_transposeV(const unsigned short* __restrict__ qkv,
                             unsigned short* __restrict__ vt) {
    __shared__ unsigned short tile[64][65];
    const int b = blockIdx.x >> 2, g = blockIdx.x & 3;
    const int s0 = blockIdx.y * 64, d0 = blockIdx.z * 64;
    const int tx = threadIdx.x & 63, ty0 = threadIdx.x >> 6;
    const unsigned short* src = qkv + (size_t)(b * T_ + s0) * NPAD + 2560 + g * 128 + d0;
#pragma unroll
    for (int r = 0; r < 16; ++r) {
        int ty = ty0 * 16 + r;
        tile[ty][tx] = src[(size_t)ty * NPAD + tx];
    }
    __syncthreads();
    unsigned short* dstp = vt + ((size_t)(b * GG + g) * 128 + d0) * T_ + s0;
#pragma unroll
    for (int r = 0; r < 16; ++r) {
        int ty = ty0 * 16 + r;
        dstp[(size_t)ty * T_ + tx] = tile[tx][ty];
    }
}

// ---------------- flash attention + gate ------------------------------------------
// 8 waves / 512 thr per block: waves 0-3 compute q-tile pr, waves 4-7 compute 31-pr,
// SHARING one K/V staging stream (loop runs 32-pr tiles; short segment skips compute
// but keeps staging+barriers). Ps stride-64 XOR-swizzled -> LDS exactly 80KB = 2 blk/CU.
// Co-residency balance: blocks i and i+256 get pr and 15-pr (tile-sum 49 constant).
__launch_bounds__(512, 4)
__global__ void k_attn(const unsigned short* __restrict__ qkv,
                       const unsigned short* __restrict__ vt,
                       unsigned short* __restrict__ ao) {
    __shared__ unsigned short Ks[2][64 * 128];   // 16KB each
    __shared__ unsigned short Vs[2][128 * 64];   // 16KB each
    __shared__ unsigned short Ps[8][16 * 64];    // 2KB per wave, XOR-swizzled slots
    const int t = threadIdx.x;
    const int lane = t & 63;
    const int wid  = t >> 6;              // 0..7
    const int id = blockIdx.x;
    const int bg = id & 7;                // -> XCD
    const int hh = (id >> 3) & 3;
    const int prx = (id >> 5) & 7;
    const int pr = (id & 256) ? (15 - prx) : prx;   // co-resident blocks sum to 15
    const int b = bg >> 2, g = bg & 3, h = g * 4 + hh;
    const int fro = lane & 15, fk = lane >> 4;
    const int rbase = fk * 4;

    const int qt  = (wid < 4) ? pr : 31 - pr;       // this wave's q-tile
    const int wq  = wid & 3;
    const int q0w = qt * 64 + wq * 16;
    const int nt_own  = qt + 1;
    const int nt_loop = 32 - pr;

    const unsigned short* kg0 = qkv + (size_t)(b * T_) * NPAD + 2048 + g * 128;
    const unsigned short* vg0 = vt + (size_t)(b * GG + g) * 128 * T_;

    // Q fragments
    short8 qf[4];
    const unsigned short* qp = qkv + (size_t)(b * T_ + q0w + fro) * NPAD + h * 128 + fk * 8;
#pragma unroll
    for (int kb = 0; kb < 4; ++kb) qf[kb] = *(const short8*)(qp + kb * 32);

    float m_r[4], l_r[4];
    f32x4 o[8];
#pragma unroll
    for (int r = 0; r < 4; ++r) { m_r[r] = -1e30f; l_r[r] = 0.f; }
#pragma unroll
    for (int d = 0; d < 8; ++d) o[d] = (f32x4){0.f, 0.f, 0.f, 0.f};

    // staging: 16 K-chunks + 16 V-chunks over 8 waves -> 2 each
    const int cp0 = wid * 2;
    int cur = 0;

    // prologue: stage tile 0
#pragma unroll
    for (int p = 0; p < 2; ++p) {
        const int cp = cp0 + p;
        const int kr = cp * 4 + (lane >> 4);
        const int sK = lane & 15;
        gl_lds16(kg0 + (size_t)kr * NPAD + (size_t)((sK ^ (kr & 7)) * 8), &Ks[cur][cp * 512]);
        const int d  = cp * 8 + (lane >> 3);
        const int sV = lane & 7;
        gl_lds16(vg0 + (size_t)d * T_ + (size_t)((sV ^ (d & 7)) * 8), &Vs[cur][cp * 512]);
    }
    __syncthreads();

    for (int ti = 0; ti < nt_loop; ++ti) {
        if (ti + 1 < nt_loop) {
            const int sn = (ti + 1) * 64;
#pragma unroll
            for (int p = 0; p < 2; ++p) {
                const int cp = cp0 + p;
                const int kr = cp * 4 + (lane >> 4);
                const int sK = lane & 15;
                gl_lds16(kg0 + (size_t)(sn + kr) * NPAD + (size_t)((sK ^ (kr & 7)) * 8), &Ks[cur ^ 1][cp * 512]);
                const int d  = cp * 8 + (lane >> 3);
                const int sV = lane & 7;
                gl_lds16(vg0 + (size_t)d * T_ + sn + (size_t)((sV ^ (d & 7)) * 8), &Vs[cur ^ 1][cp * 512]);
            }
        }
        if (ti < nt_own) {
            // ---- QK^T on buf[cur]: S[16 q][64 kv] ----
            f32x4 sc[4];
#pragma unroll
            for (int jb = 0; jb < 4; ++jb) sc[jb] = (f32x4){0.f, 0.f, 0.f, 0.f};
#pragma unroll
            for (int jb = 0; jb < 4; ++jb) {
                const int kr = jb * 16 + fro;
#pragma unroll
                for (int kb = 0; kb < 4; ++kb) {
                    short8 kf = *(const short8*)&Ks[cur][kr * 128 + 8 * ((kb * 4 + fk) ^ (kr & 7))];
                    sc[jb] = __builtin_amdgcn_mfma_f32_16x16x32_bf16(qf[kb], kf, sc[jb], 0, 0, 0);
                }
            }
            // ---- scale (log2 domain) + causal mask ----
            const bool domask = (ti == qt);
#pragma unroll
            for (int jb = 0; jb < 4; ++jb)
#pragma unroll
                for (int r = 0; r < 4; ++r) {
                    float v = sc[jb][r] * SCALE2_;
                    if (domask && (jb * 16 + fro) > (wq * 16 + rbase + r)) v = -1e30f;
                    sc[jb][r] = v;
                }
            // ---- online softmax (DPP 16-lane reductions) ----
            float mx[4], fs[4], rs[4];
#pragma unroll
            for (int r = 0; r < 4; ++r)
                mx[r] = fmaxf(fmaxf(sc[0][r], sc[1][r]), fmaxf(sc[2][r], sc[3][r]));
            red16_max(mx);
#pragma unroll
            for (int r = 0; r < 4; ++r) {
                float mn = fmaxf(m_r[r], mx[r]);
                fs[r] = exp2f(m_r[r] - mn);
                m_r[r] = mn;
            }
#pragma unroll
            for (int jb = 0; jb < 4; ++jb)
#pragma unroll
                for (int r = 0; r < 4; ++r) sc[jb][r] = exp2f(sc[jb][r] - m_r[r]);
#pragma unroll
            for (int r = 0; r < 4; ++r)
                rs[r] = (sc[0][r] + sc[1][r]) + (sc[2][r] + sc[3][r]);
            red16_sum(rs);
#pragma unroll
            for (int r = 0; r < 4; ++r) l_r[r] = l_r[r] * fs[r] + rs[r];
#pragma unroll
            for (int d = 0; d < 8; ++d)
#pragma unroll
                for (int r = 0; r < 4; ++r) o[d][r] *= fs[r];
            // ---- P -> LDS (transpose to A-layout, XOR-swizzled 16B slots) ----
            unsigned short* pw = &Ps[wid][0];
#pragma unroll
            for (int jb = 0; jb < 4; ++jb)
#pragma unroll
                for (int r = 0; r < 4; ++r) {
                    const int row = rbase + r;
                    const int slot = jb * 2 + (fro >> 3);
                    pw[row * 64 + ((slot ^ (row & 7)) * 8 + (fro & 7))] = f2bf(sc[jb][r]);
                }
            asm volatile("s_waitcnt lgkmcnt(0)" ::: "memory");
            __builtin_amdgcn_sched_barrier(0);
            short8 pa[2];
#pragma unroll
            for (int ks = 0; ks < 2; ++ks)
                pa[ks] = *(const short8*)&Ps[wid][fro * 64 + ((ks * 4 + fk) ^ (fro & 7)) * 8];
            // ---- PV on buf[cur] ----
#pragma unroll
            for (int ks = 0; ks < 2; ++ks)
#pragma unroll
                for (int db = 0; db < 8; ++db) {
                    const int d = db * 16 + fro;
                    short8 vf = *(const short8*)&Vs[cur][d * 64 + 8 * ((ks * 4 + fk) ^ (d & 7))];
                    o[db] = __builtin_amdgcn_mfma_f32_16x16x32_bf16(pa[ks], vf, o[db], 0, 0, 0);
                }
        }
        __syncthreads();
        cur ^= 1;
    }
    // ---- epilogue: 1/l, sigmoid gate, store bf16 ----
#pragma unroll
    for (int r = 0; r < 4; ++r) {
        const int qrow = q0w + rbase + r;
        float gv = bf2f(qkv[(size_t)(b * T_ + qrow) * NPAD + QKVD + h]);
        float sg = 1.f / (1.f + __expf(-gv));
        float invl = sg / l_r[r];
        unsigned short* orow = ao + (size_t)(b * T_ + qrow) * 2048 + h * 128;
#pragma unroll
        for (int db = 0; db < 8; ++db)
            orow[db * 16 + fro] = f2bf(o[db][r] * invl);
    }
}

extern "C" void kernel_launch(void* const* d_in, const int* in_sizes, int n_in,
                              void* d_out, int out_size, void* d_ws, size_t ws_size,
                              hipStream_t stream) {
    const float* x      = (const float*)d_in[0];
    const float* cosT   = (const float*)d_in[1];
    const float* sinT   = (const float*)d_in[2];
    const float* W_attn = (const float*)d_in[3];
    const float* qw     = (const float*)d_in[4];
    const float* kw     = (const float*)d_in[5];
    const float* W_proj = (const float*)d_in[6];

    char* ws = (char*)d_ws;
    const size_t OFF_XB   = 0;                       // 4096*2048*2   = 16777216
    const size_t OFF_WAB  = 16777216;                // 3200*2048*2   = 13107200
    const size_t OFF_WPB  = 29884416;                // 2048*2048*2   =  8388608
    const size_t OFF_QKV  = 38273024;                // 4096*3200*2   = 26214400
    const size_t OFF_VT   = 64487424;                // 2*4*128*2048*2=  4194304
    const size_t OFF_AO   = 68681728;                // 4096*2048*2   = 16777216
    const size_t NEED     = 85458944;
    if (ws_size < NEED) return;

    unsigned short* xb   = (unsigned short*)(ws + OFF_XB);
    unsigned short* wab  = (unsigned short*)(ws + OFF_WAB);
    unsigned short* wpb  = (unsigned short*)(ws + OFF_WPB);
    unsigned short* qkvb = (unsigned short*)(ws + OFF_QKV);
    unsigned short* vtb  = (unsigned short*)(ws + OFF_VT);
    unsigned short* aob  = (unsigned short*)(ws + OFF_AO);

    k_convert<<<8192, 256, 0, stream>>>(x,      xb,  2097152, 2097152);
    k_convert<<<6400, 256, 0, stream>>>(W_attn, wab, 1581056, 1638400);
    k_convert<<<4096, 256, 0, stream>>>(W_proj, wpb, 1048576, 1048576);
    k_gemm8<256, unsigned short><<<dim3(16, 13), 512, 0, stream>>>(xb, wab, qkvb, 2048, 2048, 2048, NPAD, NPAD);
    k_normrope<<<20480, 256, 0, stream>>>(qkvb, cosT, sinT, qw, kw);
    k_transposeV<<<dim3(8, 32, 2), 256, 0, stream>>>(qkvb, vtb);
    k_attn<<<512, 512, 0, stream>>>(qkvb, vtb, aob);
    k_gemm8<128, float><<<dim3(32, 8), 512, 0, stream>>>(aob, wpb, (float*)d_out, 2048, 2048, 2048, 2048, 2048);
}